// Round 4
// baseline (409.690 us; speedup 1.0000x reference)
//
#include <hip/hip_runtime.h>
#include <hip/hip_cooperative_groups.h>
#include <math.h>

namespace cg = cooperative_groups;

#define B_ 128
#define G_ 16
#define A_ 8732
#define C_ 21
#define THR_ 0.5f
#define NEG_POS_ 3
#define VAR0_ 0.1f
#define VAR1_ 0.2f

#define BA_    (B_ * A_)            // 1,117,696
#define GRID_  256                  // 1 block per CU (cooperative co-residency)
#define NTHR_  1024                 // 16 waves per block
#define NW_    (NTHR_ / 64)         // 16
#define CHA_   512                  // anchors per chunk
#define NCH_   (BA_ / CHA_)         // 2183 chunks, exact
#define CV4_   (CHA_ * C_ / 4)      // 2688 float4 per chunk buffer (43008 B)
#define NPT_   ((A_ + NTHR_ - 1) / NTHR_)   // 9 aux values/thread in phase D

// async global->LDS, 16B per lane; LDS dest must be (and is) wave-uniform
// base + lane*16 (linear staging order). No VGPR round-trip -> no spill.
__device__ __forceinline__ void stage16(const float4* g, float4* l) {
    __builtin_amdgcn_global_load_lds(
        (const __attribute__((address_space(1))) void*)g,
        (__attribute__((address_space(3))) void*)l,
        16, 0, 0);
}

// phase A (ov/gi) and phase C (stage) never live at the same time -> union
union SMem {
    struct { float ov[A_]; unsigned char gi[A_]; } ph1;   // 43660 B
    float4 stage[2][CV4_];                                // 86016 B
};

// ---------------------------------------------------------------------------
// Single cooperative kernel, grid = 256 x 1024 (1 block/CU, 16 waves/CU).
//  A (blocks 0-127): per-batch IoU matching (verified logic) -> match, npos.
//  C (all blocks)  : loss over 512-anchor chunks, grid-strided; conf staged
//                    via async global_load_lds, double-buffered.
//  D (blocks 0-127): per-batch hard-negative mining (verified binary search).
//  E (block 0)     : final reduce -> out.
// ---------------------------------------------------------------------------
__global__ __launch_bounds__(NTHR_, 4) void k_all(
    const float* __restrict__ pred_off,   // B,A,4
    const float* __restrict__ pred_conf,  // B,A,C
    const float* __restrict__ tboxes,     // B,G,4 (point form)
    const int*   __restrict__ tlabels,    // B,G
    const float* __restrict__ anchors,    // A,4 (center form)
    int*         __restrict__ match,      // BA
    float*       __restrict__ aux,        // BA
    int*         __restrict__ npos_b,     // B
    float*       __restrict__ ploc_b,     // GRID_
    float*       __restrict__ pcls_b,     // GRID_
    float*       __restrict__ scls_b,     // B
    float*       __restrict__ out)        // 2
{
    cg::grid_group gridg = cg::this_grid();
    const int tid  = threadIdx.x;
    const int lane = tid & 63;
    const int w    = tid >> 6;            // 0..15
    const int bid  = blockIdx.x;

    __shared__ SMem sm;
    __shared__ float s_boxlds[G_ * 4];
    __shared__ int   s_lab[G_];
    __shared__ unsigned long long s_gb[NW_ * G_];
    __shared__ int   s_forced[G_];
    __shared__ int   s_cnt[NW_];
    __shared__ int   s_c[2][NW_];
    __shared__ float s_r0[NW_], s_r1[NW_], s_r3[NW_];
    __shared__ int   s_r2[NW_];

    // ================= Phase A: matching (blocks 0..127) =================
    if (bid < B_) {
        const int b = bid;
        if (tid < G_ * 4) s_boxlds[tid] = tboxes[b * G_ * 4 + tid];
        if (tid < G_)     s_lab[tid]    = tlabels[b * G_ + tid];
        __syncthreads();

        float bx0[G_], by0[G_], bx1[G_], by1[G_], bar[G_];
        #pragma unroll
        for (int g = 0; g < G_; ++g) {
            bx0[g] = s_boxlds[g * 4 + 0];
            by0[g] = s_boxlds[g * 4 + 1];
            bx1[g] = s_boxlds[g * 4 + 2];
            by1[g] = s_boxlds[g * 4 + 3];
            bar[g] = (bx1[g] - bx0[g]) * (by1[g] - by0[g]);
        }

        unsigned long long gb[G_];
        #pragma unroll
        for (int g = 0; g < G_; ++g) gb[g] = 0ull;

        for (int a = tid; a < A_; a += NTHR_) {
            float4 an = ((const float4*)anchors)[a];
            float ax0 = an.x - an.z * 0.5f, ay0 = an.y - an.w * 0.5f;
            float ax1 = an.x + an.z * 0.5f, ay1 = an.y + an.w * 0.5f;
            float area_b = (ax1 - ax0) * (ay1 - ay0);
            float bov = -1.f; int bg = 0;
            #pragma unroll
            for (int g = 0; g < G_; ++g) {
                float tlx = fmaxf(bx0[g], ax0);
                float tly = fmaxf(by0[g], ay0);
                float brx = fminf(bx1[g], ax1);
                float bry = fminf(by1[g], ay1);
                float wdt = fmaxf(brx - tlx, 0.f);
                float hgt = fmaxf(bry - tly, 0.f);
                float inter = wdt * hgt;
                float iou = inter / (bar[g] + area_b - inter);
                if (iou > bov) { bov = iou; bg = g; }   // first g wins on ties
                unsigned long long pk =
                    ((unsigned long long)__float_as_uint(iou) << 32) |
                    (unsigned)(~(unsigned)a);           // max iou, min a on ties
                if (pk > gb[g]) gb[g] = pk;
            }
            sm.ph1.ov[a] = bov;
            sm.ph1.gi[a] = (unsigned char)bg;
        }

        #pragma unroll
        for (int g = 0; g < G_; ++g) {
            #pragma unroll
            for (int off = 32; off > 0; off >>= 1) {
                unsigned long long o = __shfl_down(gb[g], off);
                if (o > gb[g]) gb[g] = o;
            }
        }
        if (lane == 0) {
            #pragma unroll
            for (int g = 0; g < G_; ++g) s_gb[w * G_ + g] = gb[g];
        }
        __syncthreads();
        if (tid < G_) {
            unsigned long long m = 0ull;
            #pragma unroll
            for (int wv = 0; wv < NW_; ++wv) {
                unsigned long long v = s_gb[wv * G_ + tid];
                if (v > m) m = v;
            }
            s_forced[tid] = (int)(~(unsigned)(m & 0xFFFFFFFFull));
        }
        __syncthreads();
        if (tid == 0) {
            for (int g = 0; g < G_; ++g) {      // ascending g, last write wins
                int a = s_forced[g];
                sm.ph1.ov[a] = 1.0f;
                sm.ph1.gi[a] = (unsigned char)g;
            }
        }
        __syncthreads();

        int cnt = 0;
        for (int a = tid; a < A_; a += NTHR_) {
            float ov = sm.ph1.ov[a];
            int g = sm.ph1.gi[a];
            int conf = (ov < THR_) ? 0 : (s_lab[g] + 1);
            match[b * A_ + a] = conf | (g << 8);
            cnt += (conf > 0);
        }
        #pragma unroll
        for (int off = 32; off > 0; off >>= 1) cnt += __shfl_down(cnt, off);
        if (lane == 0) s_cnt[w] = cnt;
        __syncthreads();
        if (tid == 0) {
            int t = 0;
            #pragma unroll
            for (int wv = 0; wv < NW_; ++wv) t += s_cnt[wv];
            npos_b[b] = t;
        }
    }
    gridg.sync();

    // ================= Phase C: loss (all blocks, grid-stride chunks) =====
    {
        float lloc = 0.f, pnll = 0.f;
        const float4* gbase = (const float4*)pred_conf;
        int cur = 0;
        int c = bid;

        // prologue: async-stage chunk bid into buf 0 (no VGPR round-trip)
        {
            const float4* src = gbase + (size_t)c * CV4_;
            #pragma unroll
            for (int j = 0; j < 3; ++j) {
                int idx = tid + j * NTHR_;
                if (idx < CV4_) stage16(src + idx, &sm.stage[0][idx]);
            }
        }
        int mkcur = (tid < CHA_) ? match[c * CHA_ + tid] : 0;
        __syncthreads();                      // implicit vmcnt(0) drain

        for (; c < NCH_; c += GRID_) {
            const int cn = c + GRID_;
            const bool hasnext = cn < NCH_;
            int mknext = 0;
            if (hasnext) {
                const float4* src = gbase + (size_t)cn * CV4_;
                #pragma unroll
                for (int j = 0; j < 3; ++j) {
                    int idx = tid + j * NTHR_;
                    if (idx < CV4_) stage16(src + idx, &sm.stage[cur ^ 1][idx]);
                }
                if (tid < CHA_) mknext = match[cn * CHA_ + tid];
            }

            // ---- compute chunk c from buf[cur] (threads 0..511) ----
            if (tid < CHA_) {
                const float* sc = (const float*)&sm.stage[cur][0] + tid * C_;
                float m = sc[0];
                #pragma unroll
                for (int cc = 1; cc < C_; ++cc) m = fmaxf(m, sc[cc]);
                float s = 0.f;
                #pragma unroll
                for (int cc = 0; cc < C_; ++cc) s += __expf(sc[cc] - m);
                float lse = m + __logf(s);

                const int i    = c * CHA_ + tid;
                const int conf = mkcur & 0xff;
                const int g    = mkcur >> 8;
                float xc  = sc[conf];                 // single dynamic LDS read
                float nll = lse - xc;
                bool  pos = conf > 0;
                aux[i] = pos ? 0.f : nll;

                if (pos) {
                    pnll += nll;
                    int b = i / A_;                   // magic-mul const div
                    int a = i - b * A_;
                    float4 an = ((const float4*)anchors)[a];
                    float4 bx = ((const float4*)tboxes)[b * G_ + g];
                    float gcx = (bx.x + bx.z) * 0.5f, gcy = (bx.y + bx.w) * 0.5f;
                    float gw = bx.z - bx.x, gh = bx.w - bx.y;
                    float l0 = (gcx - an.x) / (an.z * VAR0_);
                    float l1 = (gcy - an.y) / (an.w * VAR0_);
                    float l2 = logf(gw / an.z) / VAR1_;
                    float l3 = logf(gh / an.w) / VAR1_;
                    float4 p = ((const float4*)pred_off)[i];
                    float d, ad;
                    d = p.x - l0; ad = fabsf(d); lloc += (ad < 1.f) ? 0.5f * d * d : ad - 0.5f;
                    d = p.y - l1; ad = fabsf(d); lloc += (ad < 1.f) ? 0.5f * d * d : ad - 0.5f;
                    d = p.z - l2; ad = fabsf(d); lloc += (ad < 1.f) ? 0.5f * d * d : ad - 0.5f;
                    d = p.w - l3; ad = fabsf(d); lloc += (ad < 1.f) ? 0.5f * d * d : ad - 0.5f;
                }
            }

            __syncthreads();   // drains vmcnt: buf[cur^1] staged AND all reads of buf[cur] done
            cur ^= 1;
            mkcur = mknext;
        }

        #pragma unroll
        for (int off = 32; off > 0; off >>= 1) {
            lloc += __shfl_down(lloc, off);
            pnll += __shfl_down(pnll, off);
        }
        if (lane == 0) { s_r0[w] = lloc; s_r1[w] = pnll; }
        __syncthreads();
        if (tid == 0) {
            float L = 0.f, P = 0.f;
            #pragma unroll
            for (int wv = 0; wv < NW_; ++wv) { L += s_r0[wv]; P += s_r1[wv]; }
            ploc_b[bid] = L;
            pcls_b[bid] = P;
        }
    }
    gridg.sync();

    // ================= Phase D: hard-negative mining (blocks 0..127) ======
    if (bid < B_) {
        const int b = bid;
        unsigned u[NPT_];
        #pragma unroll
        for (int j = 0; j < NPT_; ++j) {
            int a = tid + j * NTHR_;
            u[j] = (a < A_) ? __float_as_uint(aux[(size_t)b * A_ + a]) : 0u;
        }

        const int K = min(NEG_POS_ * npos_b[b], A_ - 1);

        unsigned lo = 0u, hi = 0x7f800000u;
        int it = 0;
        while (lo < hi) {
            unsigned mid = (lo + hi) >> 1;
            int cx = 0;
            #pragma unroll
            for (int j = 0; j < NPT_; ++j) cx += (u[j] > mid);
            #pragma unroll
            for (int off = 32; off > 0; off >>= 1) cx += __shfl_down(cx, off);
            if (lane == 0) s_c[it & 1][w] = cx;
            __syncthreads();
            int total = 0;
            #pragma unroll
            for (int wv = 0; wv < NW_; ++wv) total += s_c[it & 1][wv];
            if (total >= K) lo = mid + 1; else hi = mid;
            ++it;
        }
        // lo == bit pattern of T = K-th largest aux value

        int selc = 0; float selsm = 0.f;
        #pragma unroll
        for (int j = 0; j < NPT_; ++j) {
            if (u[j] > lo) { selc++; selsm += __uint_as_float(u[j]); }
        }
        #pragma unroll
        for (int off = 32; off > 0; off >>= 1) {
            selc  += __shfl_down(selc, off);
            selsm += __shfl_down(selsm, off);
        }
        if (lane == 0) { s_r2[w] = selc; s_r3[w] = selsm; }
        __syncthreads();
        if (tid == 0) {
            int ct = 0; float st = 0.f;
            #pragma unroll
            for (int wv = 0; wv < NW_; ++wv) { ct += s_r2[wv]; st += s_r3[wv]; }
            float T = __uint_as_float(lo);
            scls_b[b] = st + (float)(K - ct) * T;
        }
    }
    gridg.sync();

    // ================= Phase E: final reduce (block 0) ====================
    if (bid == 0) {
        float L  = (tid < GRID_) ? ploc_b[tid] : 0.f;
        float Cc = (tid < GRID_) ? pcls_b[tid] : 0.f;
        if (tid < B_) Cc += scls_b[tid];
        float n  = (tid < B_) ? (float)npos_b[tid] : 0.f;
        #pragma unroll
        for (int off = 32; off > 0; off >>= 1) {
            L  += __shfl_down(L, off);
            Cc += __shfl_down(Cc, off);
            n  += __shfl_down(n, off);
        }
        if (lane == 0) { s_r0[w] = L; s_r1[w] = Cc; s_r3[w] = n; }
        __syncthreads();
        if (tid == 0) {
            float Lt = 0.f, Ct = 0.f, Nt = 0.f;
            #pragma unroll
            for (int wv = 0; wv < NW_; ++wv) { Lt += s_r0[wv]; Ct += s_r1[wv]; Nt += s_r3[wv]; }
            out[0] = Lt / Nt;
            out[1] = Ct / Nt;
        }
    }
}

// ---------------------------------------------------------------------------
extern "C" void kernel_launch(void* const* d_in, const int* in_sizes, int n_in,
                              void* d_out, int out_size, void* d_ws, size_t ws_size,
                              hipStream_t stream) {
    const float* pred_off  = (const float*)d_in[0];  // B,A,4
    const float* pred_conf = (const float*)d_in[1];  // B,A,C
    const float* tboxes    = (const float*)d_in[2];  // B,G,4
    const int*   tlabels   = (const int*)  d_in[3];  // B,G
    const float* anchors   = (const float*)d_in[4];  // A,4
    float* out = (float*)d_out;

    // workspace layout (16B-aligned pieces; every word fully rewritten
    // each iteration -> re-poison safe)
    char* ws = (char*)d_ws;
    int*   match_ws = (int*)ws;   ws += (size_t)BA_ * sizeof(int);
    float* aux_ws   = (float*)ws; ws += (size_t)BA_ * sizeof(float);
    float* ploc_ws  = (float*)ws; ws += (size_t)GRID_ * sizeof(float);
    float* pcls_ws  = (float*)ws; ws += (size_t)GRID_ * sizeof(float);
    float* scls_ws  = (float*)ws; ws += (size_t)B_ * sizeof(float);
    int*   npos_ws  = (int*)ws;

    void* args[] = {
        (void*)&pred_off, (void*)&pred_conf, (void*)&tboxes,
        (void*)&tlabels,  (void*)&anchors,
        (void*)&match_ws, (void*)&aux_ws, (void*)&npos_ws,
        (void*)&ploc_ws,  (void*)&pcls_ws, (void*)&scls_ws,
        (void*)&out
    };
    hipLaunchCooperativeKernel((void*)k_all, dim3(GRID_), dim3(NTHR_),
                               args, 0, stream);
}

// Round 5
// 226.556 us; speedup vs baseline: 1.8083x; 1.8083x over previous
//
#include <hip/hip_runtime.h>
#include <math.h>

#define B_ 128
#define G_ 16
#define A_ 8732
#define C_ 21
#define THR_ 0.5f
#define NEG_POS_ 3
#define VAR0_ 0.1f
#define VAR1_ 0.2f

#define BA_     (B_ * A_)          // 1,117,696
#define NBLKL_  (BA_ / 256)        // 4366 loss blocks, one anchor per thread
#define PCH_    ((NBLKL_ + B_ - 1) / B_)   // 35 partials per select-block slice

struct Accum { float loss_loc; float loss_cls; int n_total; int done; };

// ---------------------------------------------------------------------------
// K1: per-batch matching. One 512-thread block per batch. (R1-verified)
// Block 0 additionally zeroes the accumulator (no other block touches acc
// in this kernel; k_select runs strictly after -> safe, replaces k_init).
// ---------------------------------------------------------------------------
__global__ __launch_bounds__(512) void k_match(
    const float* __restrict__ tboxes,   // B,G,4 (point form)
    const int*   __restrict__ tlabels,  // B,G
    const float* __restrict__ anchors,  // A,4 (center form)
    int*         __restrict__ match,    // B*A packed conf|gt<<8
    int*         __restrict__ num_pos,  // B
    Accum*                    acc)
{
    const int b    = blockIdx.x;
    const int tid  = threadIdx.x;
    const int lane = tid & 63;
    const int w    = tid >> 6;          // 0..7

    if (b == 0 && tid == 0) {
        acc->loss_loc = 0.f;
        acc->loss_cls = 0.f;
        acc->n_total  = 0;
        acc->done     = 0;
    }

    __shared__ float         s_ov[A_];
    __shared__ unsigned char s_gi[A_];
    __shared__ float s_boxlds[G_ * 4];
    __shared__ int   s_lab[G_];
    __shared__ unsigned long long s_gb[8 * G_];
    __shared__ int   s_forced[G_];
    __shared__ int   s_cnt[8];

    if (tid < G_ * 4) s_boxlds[tid] = tboxes[b * G_ * 4 + tid];
    if (tid < G_)     s_lab[tid]    = tlabels[b * G_ + tid];
    __syncthreads();

    float bx0[G_], by0[G_], bx1[G_], by1[G_], bar[G_];
    #pragma unroll
    for (int g = 0; g < G_; ++g) {
        bx0[g] = s_boxlds[g * 4 + 0];
        by0[g] = s_boxlds[g * 4 + 1];
        bx1[g] = s_boxlds[g * 4 + 2];
        by1[g] = s_boxlds[g * 4 + 3];
        bar[g] = (bx1[g] - bx0[g]) * (by1[g] - by0[g]);
    }

    unsigned long long gb[G_];
    #pragma unroll
    for (int g = 0; g < G_; ++g) gb[g] = 0ull;

    for (int a = tid; a < A_; a += 512) {
        float4 an = ((const float4*)anchors)[a];
        float ax0 = an.x - an.z * 0.5f, ay0 = an.y - an.w * 0.5f;
        float ax1 = an.x + an.z * 0.5f, ay1 = an.y + an.w * 0.5f;
        float area_b = (ax1 - ax0) * (ay1 - ay0);
        float bov = -1.f; int bg = 0;
        #pragma unroll
        for (int g = 0; g < G_; ++g) {
            float tlx = fmaxf(bx0[g], ax0);
            float tly = fmaxf(by0[g], ay0);
            float brx = fminf(bx1[g], ax1);
            float bry = fminf(by1[g], ay1);
            float wdt = fmaxf(brx - tlx, 0.f);
            float hgt = fmaxf(bry - tly, 0.f);
            float inter = wdt * hgt;
            float iou = inter / (bar[g] + area_b - inter);
            if (iou > bov) { bov = iou; bg = g; }   // first g wins on ties
            unsigned long long pk =
                ((unsigned long long)__float_as_uint(iou) << 32) |
                (unsigned)(~(unsigned)a);           // max iou, min a on ties
            if (pk > gb[g]) gb[g] = pk;
        }
        s_ov[a] = bov;
        s_gi[a] = (unsigned char)bg;
    }

    #pragma unroll
    for (int g = 0; g < G_; ++g) {
        #pragma unroll
        for (int off = 32; off > 0; off >>= 1) {
            unsigned long long o = __shfl_down(gb[g], off);
            if (o > gb[g]) gb[g] = o;
        }
    }
    if (lane == 0) {
        #pragma unroll
        for (int g = 0; g < G_; ++g) s_gb[w * G_ + g] = gb[g];
    }
    __syncthreads();
    if (tid < G_) {
        unsigned long long m = 0ull;
        #pragma unroll
        for (int wv = 0; wv < 8; ++wv) {
            unsigned long long v = s_gb[wv * G_ + tid];
            if (v > m) m = v;
        }
        s_forced[tid] = (int)(~(unsigned)(m & 0xFFFFFFFFull));
    }
    __syncthreads();
    if (tid == 0) {
        for (int g = 0; g < G_; ++g) {      // ascending g, last write wins
            int a = s_forced[g];
            s_ov[a] = 1.0f;
            s_gi[a] = (unsigned char)g;
        }
    }
    __syncthreads();

    int cnt = 0;
    for (int a = tid; a < A_; a += 512) {
        float ov = s_ov[a];
        int g = s_gi[a];
        int conf = (ov < THR_) ? 0 : (s_lab[g] + 1);
        match[b * A_ + a] = conf | (g << 8);
        cnt += (conf > 0);
    }
    #pragma unroll
    for (int off = 32; off > 0; off >>= 1) cnt += __shfl_down(cnt, off);
    if (lane == 0) s_cnt[w] = cnt;
    __syncthreads();
    if (tid == 0) {
        int t = 0;
        #pragma unroll
        for (int wv = 0; wv < 8; ++wv) t += s_cnt[wv];
        num_pos[b] = t;
    }
}

// ---------------------------------------------------------------------------
// K2: per-anchor loss (R1-verified). One anchor per thread; block stages its
// 256x21 conf slice into LDS via coalesced float4 copies; stride-21 scalar
// LDS reads (conflict-free); x[conf] = single dynamic LDS read.
// Per-block partials via plain stores (no atomic storm).
// ---------------------------------------------------------------------------
__global__ __launch_bounds__(256) void k_loss(
    const float* __restrict__ pred_off,   // B,A,4
    const float* __restrict__ pred_conf,  // B,A,C
    const float* __restrict__ tboxes,     // B,G,4
    const float* __restrict__ anchors,    // A,4
    const int*   __restrict__ match,      // flat BA
    float*       __restrict__ aux,        // flat BA
    float*       __restrict__ part_loc,   // NBLKL
    float*       __restrict__ part_cls)   // NBLKL
{
    const int tid  = threadIdx.x;
    const int i    = blockIdx.x * 256 + tid;   // flat anchor id, < BA_ (exact)
    const int lane = tid & 63;
    const int w    = tid >> 6;

    __shared__ float4 s_conf4[(256 * C_) / 4];   // 1344 float4 = 21504 B
    __shared__ float  s_lloc[4];
    __shared__ float  s_pnll[4];

    // ---- coalesced staging: 1344 contiguous float4 per block ----
    const float4* g4 = (const float4*)pred_conf + (size_t)blockIdx.x * (256 * C_ / 4);
    #pragma unroll
    for (int k = 0; k < 6; ++k) {
        int idx = tid + k * 256;
        if (idx < 256 * C_ / 4) s_conf4[idx] = g4[idx];
    }
    __syncthreads();

    const float* sc = (const float*)s_conf4 + tid * C_;

    int mk   = match[i];
    int conf = mk & 0xff;
    int g    = mk >> 8;

    float m = sc[0];
    #pragma unroll
    for (int c = 1; c < C_; ++c) m = fmaxf(m, sc[c]);
    float s = 0.f;
    #pragma unroll
    for (int c = 0; c < C_; ++c) s += __expf(sc[c] - m);
    float lse = m + __logf(s);

    float xc  = sc[conf];          // single dynamic LDS read
    float nll = lse - xc;
    bool  pos = conf > 0;

    float lloc = 0.f, pnll = 0.f;
    aux[i] = pos ? 0.f : nll;

    if (pos) {
        pnll = nll;
        int b = i / A_;            // const-div -> magic mul
        int a = i - b * A_;
        float4 an = ((const float4*)anchors)[a];
        float4 bx = ((const float4*)tboxes)[b * G_ + g];
        float gcx = (bx.x + bx.z) * 0.5f, gcy = (bx.y + bx.w) * 0.5f;
        float gw = bx.z - bx.x, gh = bx.w - bx.y;
        float l0 = (gcx - an.x) / (an.z * VAR0_);
        float l1 = (gcy - an.y) / (an.w * VAR0_);
        float l2 = logf(gw / an.z) / VAR1_;
        float l3 = logf(gh / an.w) / VAR1_;
        float4 p = ((const float4*)pred_off)[i];
        float d, ad;
        d = p.x - l0; ad = fabsf(d); lloc += (ad < 1.f) ? 0.5f * d * d : ad - 0.5f;
        d = p.y - l1; ad = fabsf(d); lloc += (ad < 1.f) ? 0.5f * d * d : ad - 0.5f;
        d = p.z - l2; ad = fabsf(d); lloc += (ad < 1.f) ? 0.5f * d * d : ad - 0.5f;
        d = p.w - l3; ad = fabsf(d); lloc += (ad < 1.f) ? 0.5f * d * d : ad - 0.5f;
    }

    #pragma unroll
    for (int off = 32; off > 0; off >>= 1) {
        lloc += __shfl_down(lloc, off);
        pnll += __shfl_down(pnll, off);
    }
    if (lane == 0) { s_lloc[w] = lloc; s_pnll[w] = pnll; }
    __syncthreads();
    if (tid == 0) {
        part_loc[blockIdx.x] = s_lloc[0] + s_lloc[1] + s_lloc[2] + s_lloc[3];
        part_cls[blockIdx.x] = s_pnll[0] + s_pnll[1] + s_pnll[2] + s_pnll[3];
    }
}

// ---------------------------------------------------------------------------
// K3: per-batch hard-negative mining (R1-verified binary search) + fused
// finalization: each block slice-reduces 35 of the 4366 loss partials,
// contributes 4 atomicAdds into acc, then a done-counter; the LAST block
// computes out[] (threadfence + device-scope atomics, G16-compliant).
// ---------------------------------------------------------------------------
#define NPT_ 35   // ceil(8732/256)
__global__ __launch_bounds__(256) void k_select(
    const float* __restrict__ aux,
    const int*   __restrict__ num_pos,
    const float* __restrict__ part_loc,
    const float* __restrict__ part_cls,
    Accum*                    acc,
    float*       __restrict__ out)
{
    const int b    = blockIdx.x;
    const int tid  = threadIdx.x;
    const int lane = tid & 63;
    const int w    = tid >> 6;           // 0..3

    __shared__ int   s_c[2][4];
    __shared__ int   s_cf[4];
    __shared__ float s_sf[4];
    __shared__ float s_pl, s_pc;

    // ---- slice-reduce loss partials: entries [b*PCH_, b*PCH_+PCH_) ----
    {
        float L = 0.f, P = 0.f;
        int base = b * PCH_;
        if (tid < PCH_) {
            int idx = base + tid;
            if (idx < NBLKL_) { L = part_loc[idx]; P = part_cls[idx]; }
        }
        #pragma unroll
        for (int off = 32; off > 0; off >>= 1) {
            L += __shfl_down(L, off);
            P += __shfl_down(P, off);
        }
        if (tid == 0) { s_pl = L; s_pc = P; }
    }

    unsigned u[NPT_];
    #pragma unroll
    for (int j = 0; j < NPT_; ++j) {
        int a = tid + j * 256;
        u[j] = (a < A_) ? __float_as_uint(aux[(size_t)b * A_ + a]) : 0u;
    }

    const int npos = num_pos[b];
    const int K = min(NEG_POS_ * npos, A_ - 1);

    unsigned lo = 0u, hi = 0x7f800000u;
    int it = 0;
    while (lo < hi) {
        unsigned mid = (lo + hi) >> 1;
        int c = 0;
        #pragma unroll
        for (int j = 0; j < NPT_; ++j) c += (u[j] > mid);
        #pragma unroll
        for (int off = 32; off > 0; off >>= 1) c += __shfl_down(c, off);
        if (lane == 0) s_c[it & 1][w] = c;
        __syncthreads();
        int total = s_c[it & 1][0] + s_c[it & 1][1] + s_c[it & 1][2] + s_c[it & 1][3];
        if (total >= K) lo = mid + 1; else hi = mid;
        ++it;
    }
    // lo == bit pattern of T = K-th largest value

    int c = 0; float sm = 0.f;
    #pragma unroll
    for (int j = 0; j < NPT_; ++j) {
        if (u[j] > lo) { c++; sm += __uint_as_float(u[j]); }
    }
    #pragma unroll
    for (int off = 32; off > 0; off >>= 1) {
        c  += __shfl_down(c, off);
        sm += __shfl_down(sm, off);
    }
    if (lane == 0) { s_cf[w] = c; s_sf[w] = sm; }
    __syncthreads();

    if (tid == 0) {
        int   ct = s_cf[0] + s_cf[1] + s_cf[2] + s_cf[3];
        float st = s_sf[0] + s_sf[1] + s_sf[2] + s_sf[3];
        float T  = __uint_as_float(lo);

        atomicAdd(&acc->loss_loc, s_pl);
        atomicAdd(&acc->loss_cls, s_pc + st + (float)(K - ct) * T);
        atomicAdd(&acc->n_total,  npos);
        __threadfence();                         // release our adds
        int old = atomicAdd(&acc->done, 1);
        if (old == B_ - 1) {                     // last block finalizes
            __threadfence();                     // acquire all adds
            float lloc = atomicAdd(&acc->loss_loc, 0.f);
            float lcls = atomicAdd(&acc->loss_cls, 0.f);
            float n    = (float)atomicAdd(&acc->n_total, 0);
            out[0] = lloc / n;
            out[1] = lcls / n;
        }
    }
}

// ---------------------------------------------------------------------------
extern "C" void kernel_launch(void* const* d_in, const int* in_sizes, int n_in,
                              void* d_out, int out_size, void* d_ws, size_t ws_size,
                              hipStream_t stream) {
    const float* pred_off  = (const float*)d_in[0];  // B,A,4
    const float* pred_conf = (const float*)d_in[1];  // B,A,C
    const float* tboxes    = (const float*)d_in[2];  // B,G,4
    const int*   tlabels   = (const int*)  d_in[3];  // B,G
    const float* anchors   = (const float*)d_in[4];  // A,4
    float* out = (float*)d_out;

    // workspace layout (all 16B-aligned; fully rewritten every iteration)
    char* ws = (char*)d_ws;
    int*   match_ws = (int*)ws;     ws += (size_t)BA_ * sizeof(int);
    float* aux_ws   = (float*)ws;   ws += (size_t)BA_ * sizeof(float);
    float* ploc_ws  = (float*)ws;   ws += (size_t)((NBLKL_ + 3) & ~3) * sizeof(float);
    float* pcls_ws  = (float*)ws;   ws += (size_t)((NBLKL_ + 3) & ~3) * sizeof(float);
    int*   npos_ws  = (int*)ws;     ws += (size_t)((B_ + 3) & ~3) * sizeof(int);
    Accum* acc      = (Accum*)ws;

    k_match<<<B_, 512, 0, stream>>>(tboxes, tlabels, anchors, match_ws, npos_ws, acc);
    k_loss<<<NBLKL_, 256, 0, stream>>>(pred_off, pred_conf, tboxes, anchors,
                                       match_ws, aux_ws, ploc_ws, pcls_ws);
    k_select<<<B_, 256, 0, stream>>>(aux_ws, npos_ws, ploc_ws, pcls_ws, acc, out);
}